// Round 8
// baseline (3372.342 us; speedup 1.0000x reference)
//
#include <hip/hip_runtime.h>

// Problem constants (match the reference file)
#define NNODES 50000
#define NEDGES 800000
#define FIN    128
#define NREL   8
#define NB     64
#define H1D    64
#define H2D    128
#define BN_EPS 1e-5f

// ---------------------------------------------------------------------------
// Edge counting: cnt_dr[(dst,rel)]++  and  cnt_d[dst]++
__global__ __launch_bounds__(256) void count_edges_kernel(
    const int* __restrict__ dst, const int* __restrict__ et,
    int* __restrict__ cnt_dr, int* __restrict__ cnt_d, int E)
{
    int e = blockIdx.x * 256 + threadIdx.x;
    if (e < E) {
        int t = dst[e];
        atomicAdd(&cnt_dr[t * NREL + et[e]], 1);
        atomicAdd(&cnt_d[t], 1);
    }
}

// cnt (int) -> inv (float) in place: 1/max(cnt,1)
__global__ __launch_bounds__(256) void inv_kernel(int* __restrict__ cnt_i,
                                                  float* __restrict__ invf, int n)
{
    int i = blockIdx.x * 256 + threadIdx.x;
    if (i < n) {
        int c = cnt_i[i];
        invf[i] = 1.0f / (float)(c > 1 ? c : 1);
    }
}

// ---------------------------------------------------------------------------
// Single-block exclusive scan of cnt_d[NNODES] -> off_d[NNODES+1], cur_d copy
__global__ __launch_bounds__(1024) void scan_kernel(
    const int* __restrict__ cnt_d, int* __restrict__ off_d, int* __restrict__ cur_d)
{
    __shared__ int part[1024];
    const int T = 1024;
    const int C = (NNODES + T - 1) / T;   // 49
    int t = threadIdx.x;
    int base = t * C;
    int s = 0;
    for (int i = 0; i < C; ++i) {
        int idx = base + i;
        if (idx < NNODES) s += cnt_d[idx];
    }
    part[t] = s;
    __syncthreads();
    for (int d = 1; d < T; d <<= 1) {
        int v = (t >= d) ? part[t - d] : 0;
        __syncthreads();
        part[t] += v;
        __syncthreads();
    }
    int run = (t == 0) ? 0 : part[t - 1];
    for (int i = 0; i < C; ++i) {
        int idx = base + i;
        if (idx < NNODES) {
            off_d[idx] = run;
            cur_d[idx] = run;
            run += cnt_d[idx];
        }
    }
    if (t == T - 1) off_d[NNODES] = run;
}

// Scatter: sorted_pk[pos] = src*8 + rel, bucketed by dst
__global__ __launch_bounds__(256) void scatter_kernel(
    const int* __restrict__ src, const int* __restrict__ dst,
    const int* __restrict__ et, int* __restrict__ cur_d,
    int* __restrict__ sorted_pk, int E)
{
    int e = blockIdx.x * 256 + threadIdx.x;
    if (e < E) {
        int pos = atomicAdd(&cur_d[dst[e]], 1);
        sorted_pk[pos] = src[e] * NREL + et[e];
    }
}

// ---------------------------------------------------------------------------
// GEMM1: [N,128] @ [128, 9*64]. r<8 -> h1t[N, r*64..]; r==8 -> agg1[N,64]+b1
// Tile 256x64, BK=16 double-buffered, 256 threads, 8x8 quad-swizzled micro.
// __launch_bounds__(256,3): cap VGPR at ~170 -> 3 waves/SIMD (was 200 -> 2).
#define G1_NBX 25   // row-blocks per XCD (25*8=200 >= 196 needed)
__global__ __launch_bounds__(256, 3) void gemm1_kernel(
    const float* __restrict__ X, const float* __restrict__ W1,
    const float* __restrict__ root1, const float* __restrict__ bias1,
    float* __restrict__ h1t, float* __restrict__ agg1, int Nn)
{
    __shared__ float As[2][16][260];   // [buf][k][m] stride 260 -> 2-way stores
    __shared__ float Bs[2][16][64];
    const int id  = blockIdx.x;
    const int xcd = id & 7;
    const int j   = id >> 3;              // 0..224
    const int r   = j / G1_NBX;           // 0..8
    const int bx  = xcd * G1_NBX + (j % G1_NBX);
    const int m0  = bx * 256;
    if (m0 >= Nn) return;                 // block-uniform exit
    const float* Bsrc = (r < 8) ? (W1 + (size_t)r * FIN * H1D) : root1;

    const int tid = threadIdx.x;
    const int ty = tid >> 3, tx = tid & 7;     // compute: row base ty*4, col base tx*4
    const int ak = tid & 15, am = tid >> 4;    // A-stage: k=ak, row=am+16i
    const int bn = tid & 63, bk = tid >> 6;    // B-stage: n=bn, k=bk+4i

    float ar[16], br[4];
    // prologue: chunk 0
#pragma unroll
    for (int i = 0; i < 16; ++i) {
        int row = m0 + am + i * 16;
        ar[i] = (row < Nn) ? X[(size_t)row * FIN + ak] : 0.f;
    }
#pragma unroll
    for (int i = 0; i < 4; ++i) br[i] = Bsrc[(size_t)(bk + i * 4) * 64 + bn];
#pragma unroll
    for (int i = 0; i < 16; ++i) As[0][ak][am + i * 16] = ar[i];
#pragma unroll
    for (int i = 0; i < 4; ++i) Bs[0][bk + i * 4][bn] = br[i];
    __syncthreads();

    float acc[8][8] = {};
    const int NCH = FIN / 16;   // 8
    for (int c = 0; c < NCH; ++c) {
        const int cur = c & 1;
        if (c + 1 < NCH) {
            const int kc = (c + 1) * 16;
#pragma unroll
            for (int i = 0; i < 16; ++i) {
                int row = m0 + am + i * 16;
                ar[i] = (row < Nn) ? X[(size_t)row * FIN + kc + ak] : 0.f;
            }
#pragma unroll
            for (int i = 0; i < 4; ++i)
                br[i] = Bsrc[(size_t)(kc + bk + i * 4) * 64 + bn];
        }
#pragma unroll
        for (int k = 0; k < 16; ++k) {
            const float4 a0 = *reinterpret_cast<const float4*>(&As[cur][k][ty * 4]);
            const float4 a1 = *reinterpret_cast<const float4*>(&As[cur][k][ty * 4 + 128]);
            const float4 b0 = *reinterpret_cast<const float4*>(&Bs[cur][k][tx * 4]);
            const float4 b1v = *reinterpret_cast<const float4*>(&Bs[cur][k][tx * 4 + 32]);
            const float a[8] = {a0.x, a0.y, a0.z, a0.w, a1.x, a1.y, a1.z, a1.w};
            const float b[8] = {b0.x, b0.y, b0.z, b0.w, b1v.x, b1v.y, b1v.z, b1v.w};
#pragma unroll
            for (int i = 0; i < 8; ++i)
#pragma unroll
                for (int jj = 0; jj < 8; ++jj) acc[i][jj] += a[i] * b[jj];
        }
        if (c + 1 < NCH) {
            const int nxt = cur ^ 1;
#pragma unroll
            for (int i = 0; i < 16; ++i) As[nxt][ak][am + i * 16] = ar[i];
#pragma unroll
            for (int i = 0; i < 4; ++i) Bs[nxt][bk + i * 4][bn] = br[i];
        }
        __syncthreads();
    }

    // rows: ty*4 + (i&3) + (i>>2)*128 ; cols: tx*4 + (j&3) + (j>>2)*32
#pragma unroll
    for (int i = 0; i < 8; ++i) {
        int row = m0 + ty * 4 + (i & 3) + (i >> 2) * 128;
        if (row >= Nn) continue;
        int col = tx * 4;
        if (r < 8) {
            float4 v0 = make_float4(acc[i][0], acc[i][1], acc[i][2], acc[i][3]);
            float4 v1 = make_float4(acc[i][4], acc[i][5], acc[i][6], acc[i][7]);
            *reinterpret_cast<float4*>(&h1t[(size_t)row * 512 + r * 64 + col]) = v0;
            *reinterpret_cast<float4*>(&h1t[(size_t)row * 512 + r * 64 + col + 32]) = v1;
        } else {
            float4 v0 = make_float4(acc[i][0] + bias1[col], acc[i][1] + bias1[col + 1],
                                    acc[i][2] + bias1[col + 2], acc[i][3] + bias1[col + 3]);
            float4 v1 = make_float4(acc[i][4] + bias1[col + 32], acc[i][5] + bias1[col + 33],
                                    acc[i][6] + bias1[col + 34], acc[i][7] + bias1[col + 35]);
            *reinterpret_cast<float4*>(&agg1[(size_t)row * H1D + col]) = v0;
            *reinterpret_cast<float4*>(&agg1[(size_t)row * H1D + col + 32]) = v1;
        }
    }
}

// ---------------------------------------------------------------------------
// Aggregation 1 (atomic-free): one wave per dst node.
__global__ __launch_bounds__(256) void agg1_gather_kernel(
    const int* __restrict__ sorted_pk, const int* __restrict__ off_d,
    const float* __restrict__ inv, const float* __restrict__ h1t,
    float* __restrict__ agg1)
{
    int d = blockIdx.x * 4 + (threadIdx.x >> 6);
    int lane = threadIdx.x & 63;
    if (d >= NNODES) return;
    int beg = off_d[d], end = off_d[d + 1];
    float acc = agg1[(size_t)d * H1D + lane];     // x@root1 + b1 already there
    for (int i = beg; i < end; ++i) {
        int k = sorted_pk[i];                      // src*8 + r
        float w = inv[d * NREL + (k & 7)];
        acc += h1t[(size_t)k * 64 + lane] * w;
    }
    agg1[(size_t)d * H1D + lane] = acc;
}

// Aggregation 2 (atomic-free): one wave per dst node, 8 rel accumulators.
__global__ __launch_bounds__(256) void agg2_gather_kernel(
    const int* __restrict__ sorted_pk, const int* __restrict__ off_d,
    const float* __restrict__ inv, const float* __restrict__ agg1,
    float* __restrict__ aggin2)
{
    int d = blockIdx.x * 4 + (threadIdx.x >> 6);
    int lane = threadIdx.x & 63;
    if (d >= NNODES) return;
    int beg = off_d[d], end = off_d[d + 1];
    float acc[NREL] = {};
    for (int i = beg; i < end; ++i) {
        int k = sorted_pk[i];
        int s = k >> 3, r = k & 7;
        float v = fmaxf(agg1[(size_t)s * H1D + lane], 0.f) * inv[d * NREL + r];
#pragma unroll
        for (int rr = 0; rr < NREL; ++rr) acc[rr] += (r == rr) ? v : 0.f;
    }
    float* row = &aggin2[(size_t)d * 512 + lane];
#pragma unroll
    for (int rr = 0; rr < NREL; ++rr) row[rr * 64] = acc[rr];
}

// ---------------------------------------------------------------------------
// GEMM2: A[n,k] = k<512 ? aggin2[n,k] : relu(agg1[n,k-512]);
//        B[k,c] = k<512 ? W2flat[k,c] : root2[k-512,c]; C = A@B + b2 -> agg2
// Tile 128x128, BK=16 double-buffered, 256 threads, 8x8 quad-swizzled micro.
// __launch_bounds__(256,3): cap VGPR at ~170 -> 3 waves/SIMD (was 200 -> 2).
__global__ __launch_bounds__(256, 3) void gemm2_kernel(
    const float* __restrict__ aggin2, const float* __restrict__ agg1,
    const float* __restrict__ W2, const float* __restrict__ root2,
    const float* __restrict__ b2, float* __restrict__ agg2, int Nn)
{
    __shared__ float As[2][16][132];
    __shared__ float Bs[2][16][128];
    const int m0 = blockIdx.x * 128;
    if (m0 >= Nn) return;
    const int tid = threadIdx.x;
    const int ty = tid >> 4, tx = tid & 15;    // row base ty*4, col base tx*4
    const int ak = tid & 15, am = tid >> 4;    // A-stage: k=ak, row=am+16i (i<8)
    const int bn = tid & 127, bk = tid >> 7;   // B-stage: n=bn, k=bk+2i (i<8)

    float ar[8], br[8];
    // prologue: chunk 0 (kc=0 < 512: aggin2 / W2)
#pragma unroll
    for (int i = 0; i < 8; ++i) {
        int row = m0 + am + i * 16;
        ar[i] = (row < Nn) ? aggin2[(size_t)row * 512 + ak] : 0.f;
    }
#pragma unroll
    for (int i = 0; i < 8; ++i) br[i] = W2[(size_t)(bk + i * 2) * H2D + bn];
#pragma unroll
    for (int i = 0; i < 8; ++i) As[0][ak][am + i * 16] = ar[i];
#pragma unroll
    for (int i = 0; i < 8; ++i) Bs[0][bk + i * 2][bn] = br[i];
    __syncthreads();

    float acc[8][8] = {};
    const int NCH = 576 / 16;   // 36
    for (int c = 0; c < NCH; ++c) {
        const int cur = c & 1;
        if (c + 1 < NCH) {
            const int kc = (c + 1) * 16;
            if (kc < 512) {
#pragma unroll
                for (int i = 0; i < 8; ++i) {
                    int row = m0 + am + i * 16;
                    ar[i] = (row < Nn) ? aggin2[(size_t)row * 512 + kc + ak] : 0.f;
                }
#pragma unroll
                for (int i = 0; i < 8; ++i)
                    br[i] = W2[(size_t)(kc + bk + i * 2) * H2D + bn];
            } else {
#pragma unroll
                for (int i = 0; i < 8; ++i) {
                    int row = m0 + am + i * 16;
                    ar[i] = (row < Nn)
                          ? fmaxf(agg1[(size_t)row * H1D + (kc - 512) + ak], 0.f) : 0.f;
                }
#pragma unroll
                for (int i = 0; i < 8; ++i)
                    br[i] = root2[(size_t)(kc - 512 + bk + i * 2) * H2D + bn];
            }
        }
#pragma unroll
        for (int k = 0; k < 16; ++k) {
            const float4 a0 = *reinterpret_cast<const float4*>(&As[cur][k][ty * 4]);
            const float4 a1 = *reinterpret_cast<const float4*>(&As[cur][k][ty * 4 + 64]);
            const float4 b0 = *reinterpret_cast<const float4*>(&Bs[cur][k][tx * 4]);
            const float4 b1v = *reinterpret_cast<const float4*>(&Bs[cur][k][tx * 4 + 64]);
            const float a[8] = {a0.x, a0.y, a0.z, a0.w, a1.x, a1.y, a1.z, a1.w};
            const float b[8] = {b0.x, b0.y, b0.z, b0.w, b1v.x, b1v.y, b1v.z, b1v.w};
#pragma unroll
            for (int i = 0; i < 8; ++i)
#pragma unroll
                for (int jj = 0; jj < 8; ++jj) acc[i][jj] += a[i] * b[jj];
        }
        if (c + 1 < NCH) {
            const int nxt = cur ^ 1;
#pragma unroll
            for (int i = 0; i < 8; ++i) As[nxt][ak][am + i * 16] = ar[i];
#pragma unroll
            for (int i = 0; i < 8; ++i) Bs[nxt][bk + i * 2][bn] = br[i];
        }
        __syncthreads();
    }

    // rows: ty*4 + (i&3) + (i>>2)*64 ; cols: tx*4 + (j&3) + (j>>2)*64
#pragma unroll
    for (int i = 0; i < 8; ++i) {
        int row = m0 + ty * 4 + (i & 3) + (i >> 2) * 64;
        if (row >= Nn) continue;
        int col = tx * 4;
        float4 v0 = make_float4(acc[i][0] + b2[col], acc[i][1] + b2[col + 1],
                                acc[i][2] + b2[col + 2], acc[i][3] + b2[col + 3]);
        float4 v1 = make_float4(acc[i][4] + b2[col + 64], acc[i][5] + b2[col + 65],
                                acc[i][6] + b2[col + 66], acc[i][7] + b2[col + 67]);
        *reinterpret_cast<float4*>(&agg2[(size_t)row * H2D + col]) = v0;
        *reinterpret_cast<float4*>(&agg2[(size_t)row * H2D + col + 64]) = v1;
    }
}

// ---------------------------------------------------------------------------
// batch is SORTED: per-batch counts via binary search
__global__ __launch_bounds__(64) void batchseg_kernel(const int* __restrict__ batch,
                                                      float* __restrict__ cntb, int Nn)
{
    __shared__ int lo_s[NB];
    int b = threadIdx.x;   // 0..63
    int lo = 0, hi = Nn;
    while (lo < hi) { int mid = (lo + hi) >> 1; if (batch[mid] < b) lo = mid + 1; else hi = mid; }
    lo_s[b] = lo;
    __syncthreads();
    int end = (b == NB - 1) ? Nn : lo_s[b + 1];
    cntb[b] = (float)(end - lo_s[b]);
}

// mean/max pooling of relu(agg2), exploiting sorted batch
__global__ __launch_bounds__(256) void pool_kernel(
    const float* __restrict__ agg2, const int* __restrict__ batch,
    float* __restrict__ psum, float* __restrict__ pmax, int Nn)
{
    int c = threadIdx.x & 127;
    int p = threadIdx.x >> 7;              // 0..1
    int n0 = blockIdx.x * 128;
    int nend = n0 + 128 < Nn ? n0 + 128 : Nn;
    float sum = 0.f, mx = 0.f;
    int cur = -1;
    for (int n = n0 + p; n < nend; n += 2) {
        int b = batch[n];
        float v = fmaxf(agg2[(size_t)n * H2D + c], 0.f);
        if (b != cur) {
            if (cur >= 0) {
                atomicAdd(&psum[cur * H2D + c], sum);
                atomicMax((int*)&pmax[cur * H2D + c], __float_as_int(mx));
            }
            cur = b; sum = 0.f; mx = 0.f;
        }
        sum += v; mx = fmaxf(mx, v);
    }
    if (cur >= 0) {
        atomicAdd(&psum[cur * H2D + c], sum);
        atomicMax((int*)&pmax[cur * H2D + c], __float_as_int(mx));
    }
}

// ---------------------------------------------------------------------------
// Whole MLP head in one block. out: pred[64*32] then emb[64*16].
__global__ __launch_bounds__(256) void head_kernel(
    const float* __restrict__ psum, const float* __restrict__ pmax,
    const float* __restrict__ cntb,
    const float* __restrict__ fc1_w, const float* __restrict__ fc1_b,
    const float* __restrict__ bn_g, const float* __restrict__ bn_b,
    const float* __restrict__ fc2_w, const float* __restrict__ fc2_b,
    const float* __restrict__ dec1_w, const float* __restrict__ dec1_b,
    const float* __restrict__ dec2_w, const float* __restrict__ dec2_b,
    float* __restrict__ out)
{
    __shared__ float gs[64 * 128];
    __shared__ float zs[64 * 64];
    __shared__ float mu[64], var_[64];
    float* es = gs;
    float* ds = gs + 1024;
    const int t = threadIdx.x;

    for (int i = t; i < 64 * 128; i += 256) {
        int b = i >> 7;
        gs[i] = psum[i] / fmaxf(cntb[b], 1.f) + pmax[i];
    }
    __syncthreads();
    for (int o = t; o < 4096; o += 256) {
        int r = o >> 6, cc = o & 63;
        float a = fc1_b[cc];
        for (int k = 0; k < 128; ++k) a += gs[r * 128 + k] * fc1_w[k * 64 + cc];
        zs[o] = a;
    }
    __syncthreads();
    if (t < 64) {
        float s = 0.f;
        for (int r = 0; r < 64; ++r) s += zs[r * 64 + t];
        float m = s * (1.f / 64.f);
        float v = 0.f;
        for (int r = 0; r < 64; ++r) { float d = zs[r * 64 + t] - m; v += d * d; }
        mu[t] = m; var_[t] = v * (1.f / 64.f);
    }
    __syncthreads();
    for (int o = t; o < 4096; o += 256) {
        int cc = o & 63;
        float z = (zs[o] - mu[cc]) / sqrtf(var_[cc] + BN_EPS) * bn_g[cc] + bn_b[cc];
        zs[o] = (z > 0.f) ? z : 0.2f * z;
    }
    __syncthreads();
    for (int o = t; o < 1024; o += 256) {
        int r = o >> 4, cc = o & 15;
        float a = fc2_b[cc];
        for (int k = 0; k < 64; ++k) a += zs[r * 64 + k] * fc2_w[k * 16 + cc];
        es[o] = a;
        out[2048 + o] = a;
    }
    __syncthreads();
    for (int o = t; o < 4096; o += 256) {
        int r = o >> 6, cc = o & 63;
        float a = dec1_b[cc];
        for (int k = 0; k < 16; ++k) a += es[r * 16 + k] * dec1_w[k * 64 + cc];
        ds[o] = (a > 0.f) ? a : 0.2f * a;
    }
    __syncthreads();
    for (int o = t; o < 2048; o += 256) {
        int r = o >> 5, cc = o & 31;
        float a = dec2_b[cc];
        for (int k = 0; k < 64; ++k) a += ds[r * 64 + k] * dec2_w[k * 32 + cc];
        out[o] = a;
    }
}

// ---------------------------------------------------------------------------
extern "C" void kernel_launch(void* const* d_in, const int* in_sizes, int n_in,
                              void* d_out, int out_size, void* d_ws, size_t ws_size,
                              hipStream_t stream)
{
    const float* x      = (const float*)d_in[0];
    const int*   eidx   = (const int*)d_in[1];
    const int*   etype  = (const int*)d_in[2];
    const int*   batch  = (const int*)d_in[3];
    const float* W1     = (const float*)d_in[4];
    const float* root1  = (const float*)d_in[5];
    const float* b1     = (const float*)d_in[6];
    const float* W2     = (const float*)d_in[7];
    const float* root2  = (const float*)d_in[8];
    const float* b2     = (const float*)d_in[9];
    const float* fc1_w  = (const float*)d_in[10];
    const float* fc1_b  = (const float*)d_in[11];
    const float* bn_g   = (const float*)d_in[12];
    const float* bn_b   = (const float*)d_in[13];
    const float* fc2_w  = (const float*)d_in[14];
    const float* fc2_b  = (const float*)d_in[15];
    const float* dec1_w = (const float*)d_in[16];
    const float* dec1_b = (const float*)d_in[17];
    const float* dec2_w = (const float*)d_in[18];
    const float* dec2_b = (const float*)d_in[19];
    float* out = (float*)d_out;

    const int* src = eidx;            // edge_index[0]
    const int* dst = eidx + NEDGES;   // edge_index[1]

    // Workspace carve-up (floats). Peak use ~142.5 MB.
    float* ws     = (float*)d_ws;
    float* h1t    = ws;                               // N*512 (reused as aggin2)
    float* agg1   = h1t  + (size_t)NNODES * 512;      // N*64
    float* agg2   = agg1 + (size_t)NNODES * H1D;      // N*128
    float* inv    = agg2 + (size_t)NNODES * H2D;      // N*8 (int cnt, then float)
    float* psum   = inv  + (size_t)NNODES * NREL;     // 64*128
    float* pmax   = psum + NB * H2D;                  // 64*128
    float* cntb   = pmax + NB * H2D;                  // 64

    // Sort scratch lives inside agg2's region (dead before gemm2 writes agg2).
    int* cnt_d     = (int*)agg2;                      // 50000
    int* off_d     = cnt_d + NNODES;                  // 50001
    int* cur_d     = off_d + NNODES + 1;              // 50000
    int* sorted_pk = cur_d + NNODES;                  // 800000  (src*8+rel)

    hipMemsetAsync(inv, 0, (size_t)NNODES * NREL * sizeof(int), stream);
    hipMemsetAsync(cnt_d, 0, NNODES * sizeof(int), stream);
    hipMemsetAsync(psum, 0, (2 * NB * H2D) * sizeof(float), stream);

    count_edges_kernel<<<(NEDGES + 255) / 256, 256, 0, stream>>>(dst, etype, (int*)inv, cnt_d, NEDGES);
    inv_kernel<<<(NNODES * NREL + 255) / 256, 256, 0, stream>>>((int*)inv, inv, NNODES * NREL);
    scan_kernel<<<1, 1024, 0, stream>>>(cnt_d, off_d, cur_d);
    scatter_kernel<<<(NEDGES + 255) / 256, 256, 0, stream>>>(src, dst, etype, cur_d, sorted_pk, NEDGES);

    // 8 XCDs * (25 row-blocks * 9 r-passes) = 1800 blocks
    gemm1_kernel<<<8 * G1_NBX * 9, 256, 0, stream>>>(x, W1, root1, b1, h1t, agg1, NNODES);

    agg1_gather_kernel<<<(NNODES + 3) / 4, 256, 0, stream>>>(sorted_pk, off_d, inv, h1t, agg1);

    // h1t is dead now; aggregation-2 writes every aggin2 slot (no memset)
    float* aggin2 = h1t;
    agg2_gather_kernel<<<(NNODES + 3) / 4, 256, 0, stream>>>(sorted_pk, off_d, inv, agg1, aggin2);

    gemm2_kernel<<<(NNODES + 127) / 128, 256, 0, stream>>>(aggin2, agg1, W2, root2, b2, agg2, NNODES);

    batchseg_kernel<<<1, 64, 0, stream>>>(batch, cntb, NNODES);
    pool_kernel<<<(NNODES + 127) / 128, 256, 0, stream>>>(agg2, batch, psum, pmax, NNODES);

    head_kernel<<<1, 256, 0, stream>>>(psum, pmax, cntb, fc1_w, fc1_b, bn_g, bn_b,
                                       fc2_w, fc2_b, dec1_w, dec1_b, dec2_w, dec2_b, out);
}

// Round 10
// 882.018 us; speedup vs baseline: 3.8234x; 3.8234x over previous
//
#include <hip/hip_runtime.h>

// Problem constants (match the reference file)
#define NNODES 50000
#define NEDGES 800000
#define FIN    128
#define NREL   8
#define NB     64
#define H1D    64
#define H2D    128
#define BN_EPS 1e-5f

// ---------------------------------------------------------------------------
// Edge counting: cnt_dr[(dst,rel)]++  and  cnt_d[dst]++
__global__ __launch_bounds__(256) void count_edges_kernel(
    const int* __restrict__ dst, const int* __restrict__ et,
    int* __restrict__ cnt_dr, int* __restrict__ cnt_d, int E)
{
    int e = blockIdx.x * 256 + threadIdx.x;
    if (e < E) {
        int t = dst[e];
        atomicAdd(&cnt_dr[t * NREL + et[e]], 1);
        atomicAdd(&cnt_d[t], 1);
    }
}

// cnt (int) -> inv (float) in place: 1/max(cnt,1)
__global__ __launch_bounds__(256) void inv_kernel(int* __restrict__ cnt_i,
                                                  float* __restrict__ invf, int n)
{
    int i = blockIdx.x * 256 + threadIdx.x;
    if (i < n) {
        int c = cnt_i[i];
        invf[i] = 1.0f / (float)(c > 1 ? c : 1);
    }
}

// ---------------------------------------------------------------------------
// Single-block exclusive scan of cnt_d[NNODES] -> off_d[NNODES+1], cur_d copy
__global__ __launch_bounds__(1024) void scan_kernel(
    const int* __restrict__ cnt_d, int* __restrict__ off_d, int* __restrict__ cur_d)
{
    __shared__ int part[1024];
    const int T = 1024;
    const int C = (NNODES + T - 1) / T;   // 49
    int t = threadIdx.x;
    int base = t * C;
    int s = 0;
    for (int i = 0; i < C; ++i) {
        int idx = base + i;
        if (idx < NNODES) s += cnt_d[idx];
    }
    part[t] = s;
    __syncthreads();
    for (int d = 1; d < T; d <<= 1) {
        int v = (t >= d) ? part[t - d] : 0;
        __syncthreads();
        part[t] += v;
        __syncthreads();
    }
    int run = (t == 0) ? 0 : part[t - 1];
    for (int i = 0; i < C; ++i) {
        int idx = base + i;
        if (idx < NNODES) {
            off_d[idx] = run;
            cur_d[idx] = run;
            run += cnt_d[idx];
        }
    }
    if (t == T - 1) off_d[NNODES] = run;
}

// Scatter: sorted_pk[pos] = src*8 + rel, bucketed by dst
__global__ __launch_bounds__(256) void scatter_kernel(
    const int* __restrict__ src, const int* __restrict__ dst,
    const int* __restrict__ et, int* __restrict__ cur_d,
    int* __restrict__ sorted_pk, int E)
{
    int e = blockIdx.x * 256 + threadIdx.x;
    if (e < E) {
        int pos = atomicAdd(&cur_d[dst[e]], 1);
        sorted_pk[pos] = src[e] * NREL + et[e];
    }
}

// ---------------------------------------------------------------------------
// GEMM1: [N,128] @ [128, 9*64]. r<8 -> h1t[N, r*64..]; r==8 -> agg1[N,64]+b1
// Tile 256x64, BK=16 double-buffered, 256 threads, 8x8 quad-swizzled micro.
// NOTE: plain __launch_bounds__(256). (256,3) made hipcc target 6 waves/EU,
// VGPR 200->84, spilled the 64-reg accumulator -> 5x regression (round 8).
#define G1_NBX 25   // row-blocks per XCD (25*8=200 >= 196 needed)
__global__ __launch_bounds__(256) void gemm1_kernel(
    const float* __restrict__ X, const float* __restrict__ W1,
    const float* __restrict__ root1, const float* __restrict__ bias1,
    float* __restrict__ h1t, float* __restrict__ agg1, int Nn)
{
    __shared__ float As[2][16][260];   // [buf][k][m] stride 260 -> 2-way stores
    __shared__ float Bs[2][16][64];
    const int id  = blockIdx.x;
    const int xcd = id & 7;
    const int j   = id >> 3;              // 0..224
    const int r   = j / G1_NBX;           // 0..8
    const int bx  = xcd * G1_NBX + (j % G1_NBX);
    const int m0  = bx * 256;
    if (m0 >= Nn) return;                 // block-uniform exit
    const float* Bsrc = (r < 8) ? (W1 + (size_t)r * FIN * H1D) : root1;

    const int tid = threadIdx.x;
    const int ty = tid >> 3, tx = tid & 7;     // compute: row base ty*4, col base tx*4
    const int ak = tid & 15, am = tid >> 4;    // A-stage: k=ak, row=am+16i
    const int bn = tid & 63, bk = tid >> 6;    // B-stage: n=bn, k=bk+4i

    float ar[16], br[4];
    // prologue: chunk 0
#pragma unroll
    for (int i = 0; i < 16; ++i) {
        int row = m0 + am + i * 16;
        ar[i] = (row < Nn) ? X[(size_t)row * FIN + ak] : 0.f;
    }
#pragma unroll
    for (int i = 0; i < 4; ++i) br[i] = Bsrc[(size_t)(bk + i * 4) * 64 + bn];
#pragma unroll
    for (int i = 0; i < 16; ++i) As[0][ak][am + i * 16] = ar[i];
#pragma unroll
    for (int i = 0; i < 4; ++i) Bs[0][bk + i * 4][bn] = br[i];
    __syncthreads();

    float acc[8][8] = {};
    const int NCH = FIN / 16;   // 8
    for (int c = 0; c < NCH; ++c) {
        const int cur = c & 1;
        if (c + 1 < NCH) {
            const int kc = (c + 1) * 16;
#pragma unroll
            for (int i = 0; i < 16; ++i) {
                int row = m0 + am + i * 16;
                ar[i] = (row < Nn) ? X[(size_t)row * FIN + kc + ak] : 0.f;
            }
#pragma unroll
            for (int i = 0; i < 4; ++i)
                br[i] = Bsrc[(size_t)(kc + bk + i * 4) * 64 + bn];
        }
#pragma unroll
        for (int k = 0; k < 16; ++k) {
            const float4 a0 = *reinterpret_cast<const float4*>(&As[cur][k][ty * 4]);
            const float4 a1 = *reinterpret_cast<const float4*>(&As[cur][k][ty * 4 + 128]);
            const float4 b0 = *reinterpret_cast<const float4*>(&Bs[cur][k][tx * 4]);
            const float4 b1v = *reinterpret_cast<const float4*>(&Bs[cur][k][tx * 4 + 32]);
            const float a[8] = {a0.x, a0.y, a0.z, a0.w, a1.x, a1.y, a1.z, a1.w};
            const float b[8] = {b0.x, b0.y, b0.z, b0.w, b1v.x, b1v.y, b1v.z, b1v.w};
#pragma unroll
            for (int i = 0; i < 8; ++i)
#pragma unroll
                for (int jj = 0; jj < 8; ++jj) acc[i][jj] += a[i] * b[jj];
        }
        if (c + 1 < NCH) {
            const int nxt = cur ^ 1;
#pragma unroll
            for (int i = 0; i < 16; ++i) As[nxt][ak][am + i * 16] = ar[i];
#pragma unroll
            for (int i = 0; i < 4; ++i) Bs[nxt][bk + i * 4][bn] = br[i];
        }
        __syncthreads();
    }

    // rows: ty*4 + (i&3) + (i>>2)*128 ; cols: tx*4 + (j&3) + (j>>2)*32
#pragma unroll
    for (int i = 0; i < 8; ++i) {
        int row = m0 + ty * 4 + (i & 3) + (i >> 2) * 128;
        if (row >= Nn) continue;
        int col = tx * 4;
        if (r < 8) {
            float4 v0 = make_float4(acc[i][0], acc[i][1], acc[i][2], acc[i][3]);
            float4 v1 = make_float4(acc[i][4], acc[i][5], acc[i][6], acc[i][7]);
            *reinterpret_cast<float4*>(&h1t[(size_t)row * 512 + r * 64 + col]) = v0;
            *reinterpret_cast<float4*>(&h1t[(size_t)row * 512 + r * 64 + col + 32]) = v1;
        } else {
            float4 v0 = make_float4(acc[i][0] + bias1[col], acc[i][1] + bias1[col + 1],
                                    acc[i][2] + bias1[col + 2], acc[i][3] + bias1[col + 3]);
            float4 v1 = make_float4(acc[i][4] + bias1[col + 32], acc[i][5] + bias1[col + 33],
                                    acc[i][6] + bias1[col + 34], acc[i][7] + bias1[col + 35]);
            *reinterpret_cast<float4*>(&agg1[(size_t)row * H1D + col]) = v0;
            *reinterpret_cast<float4*>(&agg1[(size_t)row * H1D + col + 32]) = v1;
        }
    }
}

// ---------------------------------------------------------------------------
// Aggregation 1 (atomic-free): one wave per dst node.
__global__ __launch_bounds__(256) void agg1_gather_kernel(
    const int* __restrict__ sorted_pk, const int* __restrict__ off_d,
    const float* __restrict__ inv, const float* __restrict__ h1t,
    float* __restrict__ agg1)
{
    int d = blockIdx.x * 4 + (threadIdx.x >> 6);
    int lane = threadIdx.x & 63;
    if (d >= NNODES) return;
    int beg = off_d[d], end = off_d[d + 1];
    float acc = agg1[(size_t)d * H1D + lane];     // x@root1 + b1 already there
    for (int i = beg; i < end; ++i) {
        int k = sorted_pk[i];                      // src*8 + r
        float w = inv[d * NREL + (k & 7)];
        acc += h1t[(size_t)k * 64 + lane] * w;
    }
    agg1[(size_t)d * H1D + lane] = acc;
}

// Aggregation 2 (atomic-free): one wave per dst node, 8 rel accumulators.
__global__ __launch_bounds__(256) void agg2_gather_kernel(
    const int* __restrict__ sorted_pk, const int* __restrict__ off_d,
    const float* __restrict__ inv, const float* __restrict__ agg1,
    float* __restrict__ aggin2)
{
    int d = blockIdx.x * 4 + (threadIdx.x >> 6);
    int lane = threadIdx.x & 63;
    if (d >= NNODES) return;
    int beg = off_d[d], end = off_d[d + 1];
    float acc[NREL] = {};
    for (int i = beg; i < end; ++i) {
        int k = sorted_pk[i];
        int s = k >> 3, r = k & 7;
        float v = fmaxf(agg1[(size_t)s * H1D + lane], 0.f) * inv[d * NREL + r];
#pragma unroll
        for (int rr = 0; rr < NREL; ++rr) acc[rr] += (r == rr) ? v : 0.f;
    }
    float* row = &aggin2[(size_t)d * 512 + lane];
#pragma unroll
    for (int rr = 0; rr < NREL; ++rr) row[rr * 64] = acc[rr];
}

// ---------------------------------------------------------------------------
// GEMM2: A[n,k] = k<512 ? aggin2[n,k] : relu(agg1[n,k-512]);
//        B[k,c] = k<512 ? W2flat[k,c] : root2[k-512,c]; C = A@B + b2 -> agg2
// Tile 64x128, BK=16 double-buffered, 256 threads, 4x8 micro-tile.
// Rationale (round 8): 8x8 micro (64 acc regs) -> VGPR 200 -> 2 waves/SIMD,
// latency-exposed (VALUBusy 35%). 4x8 micro (32 acc) -> ~80-100 VGPR ->
// ~5-6 waves/SIMD naturally, no launch-bounds coercion.
__global__ __launch_bounds__(256) void gemm2_kernel(
    const float* __restrict__ aggin2, const float* __restrict__ agg1,
    const float* __restrict__ W2, const float* __restrict__ root2,
    const float* __restrict__ b2, float* __restrict__ agg2, int Nn)
{
    __shared__ float As[2][16][68];    // 64 rows + pad
    __shared__ float Bs[2][16][128];
    const int m0 = blockIdx.x * 64;
    if (m0 >= Nn) return;
    const int tid = threadIdx.x;
    const int ty = tid >> 4, tx = tid & 15;    // rows ty*4+0..3, cols tx*4 and +64
    const int ak = tid & 15, am = tid >> 4;    // A-stage: k=ak, row=am+16i (i<4)
    const int bn = tid & 127, bk = tid >> 7;   // B-stage: n=bn, k=bk+2i (i<8)

    float ar[4], br[8];
    // prologue: chunk 0 (kc=0 < 512: aggin2 / W2)
#pragma unroll
    for (int i = 0; i < 4; ++i) {
        int row = m0 + am + i * 16;
        ar[i] = (row < Nn) ? aggin2[(size_t)row * 512 + ak] : 0.f;
    }
#pragma unroll
    for (int i = 0; i < 8; ++i) br[i] = W2[(size_t)(bk + i * 2) * H2D + bn];
#pragma unroll
    for (int i = 0; i < 4; ++i) As[0][ak][am + i * 16] = ar[i];
#pragma unroll
    for (int i = 0; i < 8; ++i) Bs[0][bk + i * 2][bn] = br[i];
    __syncthreads();

    float acc[4][8] = {};
    const int NCH = 576 / 16;   // 36
    for (int c = 0; c < NCH; ++c) {
        const int cur = c & 1;
        if (c + 1 < NCH) {
            const int kc = (c + 1) * 16;
            if (kc < 512) {
#pragma unroll
                for (int i = 0; i < 4; ++i) {
                    int row = m0 + am + i * 16;
                    ar[i] = (row < Nn) ? aggin2[(size_t)row * 512 + kc + ak] : 0.f;
                }
#pragma unroll
                for (int i = 0; i < 8; ++i)
                    br[i] = W2[(size_t)(kc + bk + i * 2) * H2D + bn];
            } else {
#pragma unroll
                for (int i = 0; i < 4; ++i) {
                    int row = m0 + am + i * 16;
                    ar[i] = (row < Nn)
                          ? fmaxf(agg1[(size_t)row * H1D + (kc - 512) + ak], 0.f) : 0.f;
                }
#pragma unroll
                for (int i = 0; i < 8; ++i)
                    br[i] = root2[(size_t)(kc - 512 + bk + i * 2) * H2D + bn];
            }
        }
#pragma unroll
        for (int k = 0; k < 16; ++k) {
            const float4 a0 = *reinterpret_cast<const float4*>(&As[cur][k][ty * 4]);
            const float4 b0 = *reinterpret_cast<const float4*>(&Bs[cur][k][tx * 4]);
            const float4 b1v = *reinterpret_cast<const float4*>(&Bs[cur][k][tx * 4 + 64]);
            const float a[4] = {a0.x, a0.y, a0.z, a0.w};
            const float b[8] = {b0.x, b0.y, b0.z, b0.w, b1v.x, b1v.y, b1v.z, b1v.w};
#pragma unroll
            for (int i = 0; i < 4; ++i)
#pragma unroll
                for (int jj = 0; jj < 8; ++jj) acc[i][jj] += a[i] * b[jj];
        }
        if (c + 1 < NCH) {
            const int nxt = cur ^ 1;
#pragma unroll
            for (int i = 0; i < 4; ++i) As[nxt][ak][am + i * 16] = ar[i];
#pragma unroll
            for (int i = 0; i < 8; ++i) Bs[nxt][bk + i * 2][bn] = br[i];
        }
        __syncthreads();
    }

    // rows: ty*4 + i (i<4) ; cols: tx*4 + (j&3) + (j>>2)*64
#pragma unroll
    for (int i = 0; i < 4; ++i) {
        int row = m0 + ty * 4 + i;
        if (row >= Nn) continue;
        int col = tx * 4;
        float4 v0 = make_float4(acc[i][0] + b2[col], acc[i][1] + b2[col + 1],
                                acc[i][2] + b2[col + 2], acc[i][3] + b2[col + 3]);
        float4 v1 = make_float4(acc[i][4] + b2[col + 64], acc[i][5] + b2[col + 65],
                                acc[i][6] + b2[col + 66], acc[i][7] + b2[col + 67]);
        *reinterpret_cast<float4*>(&agg2[(size_t)row * H2D + col]) = v0;
        *reinterpret_cast<float4*>(&agg2[(size_t)row * H2D + col + 64]) = v1;
    }
}

// ---------------------------------------------------------------------------
// batch is SORTED: per-batch counts via binary search
__global__ __launch_bounds__(64) void batchseg_kernel(const int* __restrict__ batch,
                                                      float* __restrict__ cntb, int Nn)
{
    __shared__ int lo_s[NB];
    int b = threadIdx.x;   // 0..63
    int lo = 0, hi = Nn;
    while (lo < hi) { int mid = (lo + hi) >> 1; if (batch[mid] < b) lo = mid + 1; else hi = mid; }
    lo_s[b] = lo;
    __syncthreads();
    int end = (b == NB - 1) ? Nn : lo_s[b + 1];
    cntb[b] = (float)(end - lo_s[b]);
}

// mean/max pooling of relu(agg2), exploiting sorted batch
__global__ __launch_bounds__(256) void pool_kernel(
    const float* __restrict__ agg2, const int* __restrict__ batch,
    float* __restrict__ psum, float* __restrict__ pmax, int Nn)
{
    int c = threadIdx.x & 127;
    int p = threadIdx.x >> 7;              // 0..1
    int n0 = blockIdx.x * 128;
    int nend = n0 + 128 < Nn ? n0 + 128 : Nn;
    float sum = 0.f, mx = 0.f;
    int cur = -1;
    for (int n = n0 + p; n < nend; n += 2) {
        int b = batch[n];
        float v = fmaxf(agg2[(size_t)n * H2D + c], 0.f);
        if (b != cur) {
            if (cur >= 0) {
                atomicAdd(&psum[cur * H2D + c], sum);
                atomicMax((int*)&pmax[cur * H2D + c], __float_as_int(mx));
            }
            cur = b; sum = 0.f; mx = 0.f;
        }
        sum += v; mx = fmaxf(mx, v);
    }
    if (cur >= 0) {
        atomicAdd(&psum[cur * H2D + c], sum);
        atomicMax((int*)&pmax[cur * H2D + c], __float_as_int(mx));
    }
}

// ---------------------------------------------------------------------------
// Whole MLP head in one block. out: pred[64*32] then emb[64*16].
__global__ __launch_bounds__(256) void head_kernel(
    const float* __restrict__ psum, const float* __restrict__ pmax,
    const float* __restrict__ cntb,
    const float* __restrict__ fc1_w, const float* __restrict__ fc1_b,
    const float* __restrict__ bn_g, const float* __restrict__ bn_b,
    const float* __restrict__ fc2_w, const float* __restrict__ fc2_b,
    const float* __restrict__ dec1_w, const float* __restrict__ dec1_b,
    const float* __restrict__ dec2_w, const float* __restrict__ dec2_b,
    float* __restrict__ out)
{
    __shared__ float gs[64 * 128];
    __shared__ float zs[64 * 64];
    __shared__ float mu[64], var_[64];
    float* es = gs;
    float* ds = gs + 1024;
    const int t = threadIdx.x;

    for (int i = t; i < 64 * 128; i += 256) {
        int b = i >> 7;
        gs[i] = psum[i] / fmaxf(cntb[b], 1.f) + pmax[i];
    }
    __syncthreads();
    for (int o = t; o < 4096; o += 256) {
        int r = o >> 6, cc = o & 63;
        float a = fc1_b[cc];
        for (int k = 0; k < 128; ++k) a += gs[r * 128 + k] * fc1_w[k * 64 + cc];
        zs[o] = a;
    }
    __syncthreads();
    if (t < 64) {
        float s = 0.f;
        for (int r = 0; r < 64; ++r) s += zs[r * 64 + t];
        float m = s * (1.f / 64.f);
        float v = 0.f;
        for (int r = 0; r < 64; ++r) { float d = zs[r * 64 + t] - m; v += d * d; }
        mu[t] = m; var_[t] = v * (1.f / 64.f);
    }
    __syncthreads();
    for (int o = t; o < 4096; o += 256) {
        int cc = o & 63;
        float z = (zs[o] - mu[cc]) / sqrtf(var_[cc] + BN_EPS) * bn_g[cc] + bn_b[cc];
        zs[o] = (z > 0.f) ? z : 0.2f * z;
    }
    __syncthreads();
    for (int o = t; o < 1024; o += 256) {
        int r = o >> 4, cc = o & 15;
        float a = fc2_b[cc];
        for (int k = 0; k < 64; ++k) a += zs[r * 64 + k] * fc2_w[k * 16 + cc];
        es[o] = a;
        out[2048 + o] = a;
    }
    __syncthreads();
    for (int o = t; o < 4096; o += 256) {
        int r = o >> 6, cc = o & 63;
        float a = dec1_b[cc];
        for (int k = 0; k < 16; ++k) a += es[r * 16 + k] * dec1_w[k * 64 + cc];
        ds[o] = (a > 0.f) ? a : 0.2f * a;
    }
    __syncthreads();
    for (int o = t; o < 2048; o += 256) {
        int r = o >> 5, cc = o & 31;
        float a = dec2_b[cc];
        for (int k = 0; k < 64; ++k) a += ds[r * 64 + k] * dec2_w[k * 32 + cc];
        out[o] = a;
    }
}

// ---------------------------------------------------------------------------
extern "C" void kernel_launch(void* const* d_in, const int* in_sizes, int n_in,
                              void* d_out, int out_size, void* d_ws, size_t ws_size,
                              hipStream_t stream)
{
    const float* x      = (const float*)d_in[0];
    const int*   eidx   = (const int*)d_in[1];
    const int*   etype  = (const int*)d_in[2];
    const int*   batch  = (const int*)d_in[3];
    const float* W1     = (const float*)d_in[4];
    const float* root1  = (const float*)d_in[5];
    const float* b1     = (const float*)d_in[6];
    const float* W2     = (const float*)d_in[7];
    const float* root2  = (const float*)d_in[8];
    const float* b2     = (const float*)d_in[9];
    const float* fc1_w  = (const float*)d_in[10];
    const float* fc1_b  = (const float*)d_in[11];
    const float* bn_g   = (const float*)d_in[12];
    const float* bn_b   = (const float*)d_in[13];
    const float* fc2_w  = (const float*)d_in[14];
    const float* fc2_b  = (const float*)d_in[15];
    const float* dec1_w = (const float*)d_in[16];
    const float* dec1_b = (const float*)d_in[17];
    const float* dec2_w = (const float*)d_in[18];
    const float* dec2_b = (const float*)d_in[19];
    float* out = (float*)d_out;

    const int* src = eidx;            // edge_index[0]
    const int* dst = eidx + NEDGES;   // edge_index[1]

    // Workspace carve-up (floats). Peak use ~142.5 MB.
    float* ws     = (float*)d_ws;
    float* h1t    = ws;                               // N*512 (reused as aggin2)
    float* agg1   = h1t  + (size_t)NNODES * 512;      // N*64
    float* agg2   = agg1 + (size_t)NNODES * H1D;      // N*128
    float* inv    = agg2 + (size_t)NNODES * H2D;      // N*8 (int cnt, then float)
    float* psum   = inv  + (size_t)NNODES * NREL;     // 64*128
    float* pmax   = psum + NB * H2D;                  // 64*128
    float* cntb   = pmax + NB * H2D;                  // 64

    // Sort scratch lives inside agg2's region (dead before gemm2 writes agg2).
    int* cnt_d     = (int*)agg2;                      // 50000
    int* off_d     = cnt_d + NNODES;                  // 50001
    int* cur_d     = off_d + NNODES + 1;              // 50000
    int* sorted_pk = cur_d + NNODES;                  // 800000  (src*8+rel)

    hipMemsetAsync(inv, 0, (size_t)NNODES * NREL * sizeof(int), stream);
    hipMemsetAsync(cnt_d, 0, NNODES * sizeof(int), stream);
    hipMemsetAsync(psum, 0, (2 * NB * H2D) * sizeof(float), stream);

    count_edges_kernel<<<(NEDGES + 255) / 256, 256, 0, stream>>>(dst, etype, (int*)inv, cnt_d, NEDGES);
    inv_kernel<<<(NNODES * NREL + 255) / 256, 256, 0, stream>>>((int*)inv, inv, NNODES * NREL);
    scan_kernel<<<1, 1024, 0, stream>>>(cnt_d, off_d, cur_d);
    scatter_kernel<<<(NEDGES + 255) / 256, 256, 0, stream>>>(src, dst, etype, cur_d, sorted_pk, NEDGES);

    // 8 XCDs * (25 row-blocks * 9 r-passes) = 1800 blocks
    gemm1_kernel<<<8 * G1_NBX * 9, 256, 0, stream>>>(x, W1, root1, b1, h1t, agg1, NNODES);

    agg1_gather_kernel<<<(NNODES + 3) / 4, 256, 0, stream>>>(sorted_pk, off_d, inv, h1t, agg1);

    // h1t is dead now; aggregation-2 writes every aggin2 slot (no memset)
    float* aggin2 = h1t;
    agg2_gather_kernel<<<(NNODES + 3) / 4, 256, 0, stream>>>(sorted_pk, off_d, inv, agg1, aggin2);

    gemm2_kernel<<<(NNODES + 63) / 64, 256, 0, stream>>>(aggin2, agg1, W2, root2, b2, agg2, NNODES);

    batchseg_kernel<<<1, 64, 0, stream>>>(batch, cntb, NNODES);
    pool_kernel<<<(NNODES + 127) / 128, 256, 0, stream>>>(agg2, batch, psum, pmax, NNODES);

    head_kernel<<<1, 256, 0, stream>>>(psum, pmax, cntb, fc1_w, fc1_b, bn_g, bn_b,
                                       fc2_w, fc2_b, dec1_w, dec1_b, dec2_w, dec2_b, out);
}